// Round 14
// baseline (3830.571 us; speedup 1.0000x reference)
//
#include <hip/hip_runtime.h>
#include <math.h>

// Conv1D(k=2,F=64,relu) -> LSTM1(H=100, relu cell, seq) -> LSTM2 (last) ->
// Dense(3) -> softmax.  B=128, T=2048, T'=2047.
//
// Round-19 = round-18 (MFMA batch-16) hardened; r18 died at infra level,
// design untested.  Fixes vs r18:
//  * A-frag load: constant-bound unrolled loops (r18's runtime-bound loop
//    runtime-indexed af[] -> scratch, rule #20).
//  * __launch_bounds__(512,1): 2 waves/SIMD -> 256-reg budget (af alone is
//    ~112 VGPRs; (512,2)'s 128 cap would spill).
// Design:
//  8 producer + 8 consumer blocks, 16 batches each; one 16x16x16f16 MFMA
//  = 16x16 tile over K=16.  Producer B-rows = [x(64)|h1(112p)] = 11 K-tiles,
//  44 MFMA/wave/step; consumer B-rows = [h1(112p)|h2(112p)] = 14 K-tiles,
//  56 MFMA.  C-layout (col=lane&15=batch, row=4*(lane>>4)+j=unit,
//  m89-family) puts all 4 gates of (unit,batch) in ONE lane -> cell fully
//  in-register, h' = one 8B frag-layout store.  A-frags prepacked per
//  (wave,lane) (row=lane&15, k=4*(lane>>4)+i).  Ring/flag protocol =
//  r14-proven, x16 width; 1 barrier/step; 2-slot frag-layout B-buffer;
//  conv on wave 7.

typedef _Float16 h2    __attribute__((ext_vector_type(2)));
typedef _Float16 f16x4 __attribute__((ext_vector_type(4)));
typedef float    f32x4 __attribute__((ext_vector_type(4)));

#define TT 2048
#define TP 2047
#define HH 100
#define G4 400
#define FF 64
#define NG 8             // batch groups (16 batches each)
#define BN 16

#define KTP 11           // producer K-tiles (176 = x64 + h112)
#define KTC 14           // consumer K-tiles (224 = h1 112 + h2 112)
#define BSTR 56          // B-buffer lane stride in halves (fits 14 tiles)
#define NW 7             // compute waves (wave 7 = conv / idle)

#define NPW (NW * 64 * 88)    // producer A-frag h2 count (44 frags x 2 h2)
#define NCW (NW * 64 * 112)   // consumer A-frag h2 count (56 frags x 2 h2)
#define CHK 64
#define NCHUNK 32
#define RINGC 4
#define CHUNK_DW (CHK * BN * 50)   // 51200 dwords per ring slot

// ws layout in h2 (4B) units
#define WS_FLAGS (NPW + NCW)       // pflag[8], aflag[8]
#define WS_RING  (WS_FLAGS + 16)

static __device__ __forceinline__ float sig(float z) {
    return 1.0f / (1.0f + __expf(-z));
}
// B-frag address (halves within a slot): element B[k][n]
static __device__ __forceinline__ int baddr(int k, int n) {
    return (16 * ((k & 15) >> 2) + n) * BSTR + (k >> 4) * 4 + (k & 3);
}

// ---------------- prep kernel: pack A-frags (f16) per (wave,lane) ----------
__global__ void prep_weights(const float* __restrict__ w1, const float* __restrict__ u1,
                             const float* __restrict__ w2, const float* __restrict__ u2,
                             h2* __restrict__ ws)
{
    const int idx = blockIdx.x * 256 + threadIdx.x;
    if (idx >= NPW + NCW) return;
    float v[2] = {0.f, 0.f};
    if (idx < NPW) {
        const int wl = idx / 88, j = idx % 88;
        const int w = wl / 64, l = wl % 64;
        const int hh = 2 * j;
        const int gi = hh / 44, r = hh % 44, kt = r / 4, e0 = r % 4;
        const int u = 16 * w + (l & 15);
#pragma unroll
        for (int e2 = 0; e2 < 2; ++e2) {
            const int k = kt * 16 + 4 * (l >> 4) + e0 + e2;
            if (u < HH) {
                const int col = gi * HH + u;
                if (k < FF) v[e2] = w1[k * G4 + col];
                else if (k - FF < HH) v[e2] = u1[(k - FF) * G4 + col];
            }
        }
    } else {
        const int j2 = idx - NPW;
        const int wl = j2 / 112, j = j2 % 112;
        const int w = wl / 64, l = wl % 64;
        const int hh = 2 * j;
        const int gi = hh / 56, r = hh % 56, kt = r / 4, e0 = r % 4;
        const int u = 16 * w + (l & 15);
#pragma unroll
        for (int e2 = 0; e2 < 2; ++e2) {
            const int k = kt * 16 + 4 * (l >> 4) + e0 + e2;
            if (u < HH) {
                const int col = gi * HH + u;
                if (k < 112) { if (k < HH) v[e2] = w2[k * G4 + col]; }
                else if (k - 112 < HH) v[e2] = u2[(k - 112) * G4 + col];
            }
        }
    }
    ws[idx] = h2{(_Float16)v[0], (_Float16)v[1]};
}

#define CELL(j, cj, hq) { \
    const float zi = aci[j] + bias[j]; \
    const float zf = acf[j] + bias[4 + j]; \
    const float zg = acg[j] + bias[8 + j]; \
    const float zo = aco[j] + bias[12 + j]; \
    cj = fmaf(sig(zf), cj, sig(zi) * fmaxf(zg, 0.f)); \
    hq = (_Float16)(sig(zo) * fmaxf(cj, 0.f)); }

#define LO16(v) __builtin_bit_cast(_Float16, (unsigned short)((v) & 0xFFFFu))
#define HI16(v) __builtin_bit_cast(_Float16, (unsigned short)((v) >> 16))

// ---------------- main kernel ----------------------------------------------
__global__ __launch_bounds__(512, 1)
void fused_lstm_kernel(const float* __restrict__ s,       // [B,T]
                       const float* __restrict__ conv_w,  // [2,1,F]
                       const float* __restrict__ conv_b,  // [F]
                       const float* __restrict__ b1,
                       const float* __restrict__ b2,
                       const float* __restrict__ dw, const float* __restrict__ db,
                       h2* __restrict__ wpk,              // A-frags + flags + ring
                       float* __restrict__ out)           // [B,3]
{
    const int tid = threadIdx.x;
    const int bb  = blockIdx.x;
    const int grp = bb & 7;
    const bool prod = bb < NG;
    const int w = tid >> 6, l = tid & 63;
    const int q = l >> 4, n = l & 15;

    int* pflag = (int*)(wpk + WS_FLAGS) + grp;
    int* aflag = (int*)(wpk + WS_FLAGS) + 8 + grp;
    unsigned* ring = (unsigned*)(wpk + WS_RING) + (size_t)grp * (RINGC * CHUNK_DW);

    __shared__ __align__(16) _Float16 Bb[2 * 64 * BSTR];   // frag-layout operand ring
    __shared__ __align__(16) float    s_win[BN * 68];      // producer s window
    __shared__ __align__(16) _Float16 hfin[112 * 16];      // consumer final h2

    for (int i = tid; i < 2 * 64 * BSTR / 2; i += 512) ((unsigned*)Bb)[i] = 0u;
    for (int i = tid; i < 112 * 16 / 2; i += 512) ((unsigned*)hfin)[i] = 0u;

    // ---- load A-frags + biases (constant-bound unrolls: regs, not scratch) ----
    f16x4 af[4 * KTC];                 // producer uses first 4*KTP
    float bias[16];
    float c0 = 0.f, c1 = 0.f, c2 = 0.f, c3 = 0.f;
    if (w < NW) {
        if (prod) {
            const float2* pa = (const float2*)(wpk + (size_t)(w * 64 + l) * 88);
#pragma unroll
            for (int i = 0; i < 4 * KTP; ++i)
                af[i] = __builtin_bit_cast(f16x4, pa[i]);
        } else {
            const float2* pa = (const float2*)(wpk + NPW + (size_t)(w * 64 + l) * 112);
#pragma unroll
            for (int i = 0; i < 4 * KTC; ++i)
                af[i] = __builtin_bit_cast(f16x4, pa[i]);
        }
        const float* bv = prod ? b1 : b2;
#pragma unroll
        for (int gi = 0; gi < 4; ++gi)
#pragma unroll
            for (int j = 0; j < 4; ++j) {
                const int u = 16 * w + 4 * q + j;
                bias[gi * 4 + j] = (u < HH) ? bv[gi * HH + u] : 0.f;
            }
    } else {
#pragma unroll
        for (int i = 0; i < 16; ++i) bias[i] = 0.f;
    }
    // conv constants (producer wave 7; lane l = filter)
    float cv0 = 0.f, cv1 = 0.f, cb0 = 0.f;
    if (prod && w == NW) { cv0 = conv_w[l]; cv1 = conv_w[FF + l]; cb0 = conv_b[l]; }
    __syncthreads();                                   // (A)

    if (prod) {
        // ================= PRODUCER: conv + LSTM1 (16 batches) ==============
        for (int k = 0; k < NCHUNK; ++k) {
            const int t0 = k * CHK;
            const int csz = (TP - t0 < CHK) ? (TP - t0) : CHK;
            if (tid == 0 && k >= RINGC) {
                int gg = 0;
                while (__hip_atomic_load(aflag, __ATOMIC_ACQUIRE,
                                         __HIP_MEMORY_SCOPE_AGENT) < k - (RINGC - 1)
                       && gg < 50000000) { ++gg; __builtin_amdgcn_s_sleep(8); }
            }
            __syncthreads();                           // (C1)
            for (int i = tid; i < BN * 68; i += 512) {
                const int nn = i / 68, jj = i % 68;
                const int ts = t0 + jj;
                s_win[i] = (ts < TT) ? s[(size_t)(BN * grp + nn) * TT + ts] : 0.f;
            }
            __syncthreads();                           // (C2)
            if (k == 0) {
                if (w == NW) {                         // x(0) into slot 0
#pragma unroll
                    for (int nn = 0; nn < BN; ++nn) {
                        const float xv = fmaxf(fmaf(s_win[nn * 68], cv0,
                                          fmaf(s_win[nn * 68 + 1], cv1, cb0)), 0.f);
                        Bb[baddr(l, nn)] = (_Float16)xv;
                    }
                }
                __syncthreads();                       // (C3, k==0 only)
            }
            for (int lt = 0; lt < csz; ++lt) {
                const int t = t0 + lt;
                _Float16* cur = Bb + (t & 1) * (64 * BSTR);
                _Float16* nxt = Bb + ((t & 1) ^ 1) * (64 * BSTR);
                if (w < NW) {
                    const float2* pb = (const float2*)(cur + l * BSTR);
                    f32x4 aci = {0.f,0.f,0.f,0.f}, acf = {0.f,0.f,0.f,0.f};
                    f32x4 acg = {0.f,0.f,0.f,0.f}, aco = {0.f,0.f,0.f,0.f};
#pragma unroll
                    for (int kt = 0; kt < KTP; ++kt) {
                        const f16x4 bf = __builtin_bit_cast(f16x4, pb[kt]);
                        aci = __builtin_amdgcn_mfma_f32_16x16x16f16(af[0*KTP+kt], bf, aci, 0,0,0);
                        acf = __builtin_amdgcn_mfma_f32_16x16x16f16(af[1*KTP+kt], bf, acf, 0,0,0);
                        acg = __builtin_amdgcn_mfma_f32_16x16x16f16(af[2*KTP+kt], bf, acg, 0,0,0);
                        aco = __builtin_amdgcn_mfma_f32_16x16x16f16(af[3*KTP+kt], bf, aco, 0,0,0);
                    }
                    const int ub = 16 * w + 4 * q;
                    if (ub < HH) {
                        _Float16 hq0, hq1, hq2, hq3;
                        CELL(0, c0, hq0) CELL(1, c1, hq1) CELL(2, c2, hq2) CELL(3, c3, hq3)
                        f16x4 hv = {hq0, hq1, hq2, hq3};          // units ub..ub+3
                        *(f16x4*)(nxt + (16 * q + n) * BSTR + (4 + w) * 4) = hv;
                        const unsigned d0 = (unsigned)__builtin_bit_cast(unsigned short, hq0)
                                          | ((unsigned)__builtin_bit_cast(unsigned short, hq1) << 16);
                        const unsigned d1 = (unsigned)__builtin_bit_cast(unsigned short, hq2)
                                          | ((unsigned)__builtin_bit_cast(unsigned short, hq3) << 16);
                        unsigned* dst = ring + (size_t)((t >> 6) & 3) * CHUNK_DW
                                             + (lt * BN + n) * 50 + (ub >> 1);
                        __hip_atomic_store(dst, d0, __ATOMIC_RELAXED, __HIP_MEMORY_SCOPE_AGENT);
                        __hip_atomic_store(dst + 1, d1, __ATOMIC_RELAXED, __HIP_MEMORY_SCOPE_AGENT);
                    }
                } else if (t + 1 < TP) {               // conv wave: x(t+1)
#pragma unroll
                    for (int nn = 0; nn < BN; ++nn) {
                        const float xv = fmaxf(fmaf(s_win[nn * 68 + lt + 1], cv0,
                                          fmaf(s_win[nn * 68 + lt + 2], cv1, cb0)), 0.f);
                        nxt[baddr(l, nn)] = (_Float16)xv;
                    }
                }
                if (lt == csz - 1)
                    asm volatile("s_waitcnt vmcnt(0)" ::: "memory");
                __syncthreads();                       // (C) one per step
            }
            if (tid == 0)
                __hip_atomic_fetch_add(pflag, 1, __ATOMIC_RELEASE,
                                       __HIP_MEMORY_SCOPE_AGENT);
        }
    } else {
        // ================= CONSUMER: LSTM2 + dense + softmax ================
        for (int k = 0; k < NCHUNK; ++k) {
            const int t0 = k * CHK;
            const int csz = (TP - t0 < CHK) ? (TP - t0) : CHK;
            if (tid == 0) {
                int gg = 0;
                while (__hip_atomic_load(pflag, __ATOMIC_ACQUIRE,
                                         __HIP_MEMORY_SCOPE_AGENT) < k + 1
                       && gg < 50000000) { ++gg; __builtin_amdgcn_s_sleep(8); }
            }
            __syncthreads();                           // chunk ready
            {   // stage h1(t0) into slot t0&1 (rows < 100; h2 region untouched)
                _Float16* st = Bb + (t0 & 1) * (64 * BSTR);
                for (int d = tid; d < BN * 50; d += 512) {
                    const int nn = d / 50, u0 = 2 * (d % 50);
                    const unsigned v = __hip_atomic_load(
                        ring + (size_t)(k & 3) * CHUNK_DW + d,
                        __ATOMIC_RELAXED, __HIP_MEMORY_SCOPE_AGENT);
                    st[baddr(u0, nn)]     = LO16(v);
                    st[baddr(u0 + 1, nn)] = HI16(v);
                }
            }
            __syncthreads();                           // staged
            for (int lt = 0; lt < csz; ++lt) {
                const int t = t0 + lt;
                _Float16* cur = Bb + (t & 1) * (64 * BSTR);
                _Float16* nxt = Bb + ((t & 1) ^ 1) * (64 * BSTR);
                // prefetch h1(t+1) (issue early, write late -- T14)
                unsigned pv0 = 0, pv1 = 0;
                const bool pf = (lt + 1 < csz);
                if (pf) {
                    const size_t base = (size_t)(k & 3) * CHUNK_DW + (size_t)(lt + 1) * BN * 50;
                    pv0 = __hip_atomic_load(ring + base + tid,
                                            __ATOMIC_RELAXED, __HIP_MEMORY_SCOPE_AGENT);
                    if (tid < BN * 50 - 512)
                        pv1 = __hip_atomic_load(ring + base + 512 + tid,
                                                __ATOMIC_RELAXED, __HIP_MEMORY_SCOPE_AGENT);
                }
                if (w < NW) {
                    const float2* pb = (const float2*)(cur + l * BSTR);
                    f32x4 aci = {0.f,0.f,0.f,0.f}, acf = {0.f,0.f,0.f,0.f};
                    f32x4 acg = {0.f,0.f,0.f,0.f}, aco = {0.f,0.f,0.f,0.f};
#pragma unroll
                    for (int kt = 0; kt < KTC; ++kt) {
                        const f16x4 bf = __builtin_bit_cast(f16x4, pb[kt]);
                        aci = __builtin_amdgcn_mfma_f32_16x16x16f16(af[0*KTC+kt], bf, aci, 0,0,0);
                        acf = __builtin_amdgcn_mfma_f32_16x16x16f16(af[1*KTC+kt], bf, acf, 0,0,0);
                        acg = __builtin_amdgcn_mfma_f32_16x16x16f16(af[2*KTC+kt], bf, acg, 0,0,0);
                        aco = __builtin_amdgcn_mfma_f32_16x16x16f16(af[3*KTC+kt], bf, aco, 0,0,0);
                    }
                    const int ub = 16 * w + 4 * q;
                    if (ub < HH) {
                        _Float16 hq0, hq1, hq2, hq3;
                        CELL(0, c0, hq0) CELL(1, c1, hq1) CELL(2, c2, hq2) CELL(3, c3, hq3)
                        f16x4 hv = {hq0, hq1, hq2, hq3};
                        *(f16x4*)(nxt + (16 * q + n) * BSTR + (7 + w) * 4) = hv;
                        if (t == TP - 1) {
                            hfin[(ub + 0) * 16 + n] = hq0;
                            hfin[(ub + 1) * 16 + n] = hq1;
                            hfin[(ub + 2) * 16 + n] = hq2;
                            hfin[(ub + 3) * 16 + n] = hq3;
                        }
                    }
                }
                if (pf) {                              // write prefetched h1(t+1)
                    {
                        const int nn = tid / 50, u0 = 2 * (tid % 50);
                        nxt[baddr(u0, nn)]     = LO16(pv0);
                        nxt[baddr(u0 + 1, nn)] = HI16(pv0);
                    }
                    if (tid < BN * 50 - 512) {
                        const int d = tid + 512;
                        const int nn = d / 50, u0 = 2 * (d % 50);
                        nxt[baddr(u0, nn)]     = LO16(pv1);
                        nxt[baddr(u0 + 1, nn)] = HI16(pv1);
                    }
                }
                __syncthreads();                       // (C) one per step
            }
            if (tid == 0)
                __hip_atomic_fetch_add(aflag, 1, __ATOMIC_RELAXED,
                                       __HIP_MEMORY_SCOPE_AGENT);
        }

        // dense + softmax (hfin written at t=2046, barrier-protected)
        if (tid < BN) {
            float lgt[3];
#pragma unroll
            for (int a = 0; a < 3; ++a) {
                float acc = db[a];
                for (int u = 0; u < HH; ++u)
                    acc = fmaf((float)hfin[u * 16 + tid], dw[u * 3 + a], acc);
                lgt[a] = acc;
            }
            const float m = fmaxf(lgt[0], fmaxf(lgt[1], lgt[2]));
            const float e0 = __expf(lgt[0] - m), e1 = __expf(lgt[1] - m), e2 = __expf(lgt[2] - m);
            const float inv = 1.0f / (e0 + e1 + e2);
            const int bout = BN * grp + tid;
            out[bout * 3 + 0] = e0 * inv;
            out[bout * 3 + 1] = e1 * inv;
            out[bout * 3 + 2] = e2 * inv;
        }
    }
}

// ---------------- launch ----------------------------------------------------
extern "C" void kernel_launch(void* const* d_in, const int* in_sizes, int n_in,
                              void* d_out, int out_size, void* d_ws, size_t ws_size,
                              hipStream_t stream) {
    const float* s      = (const float*)d_in[0];
    const float* conv_w = (const float*)d_in[1];
    const float* conv_b = (const float*)d_in[2];
    const float* w1     = (const float*)d_in[3];
    const float* u1     = (const float*)d_in[4];
    const float* b1     = (const float*)d_in[5];
    const float* w2     = (const float*)d_in[6];
    const float* u2     = (const float*)d_in[7];
    const float* b2     = (const float*)d_in[8];
    const float* dw     = (const float*)d_in[9];
    const float* db     = (const float*)d_in[10];

    h2* ws = (h2*)d_ws;
    hipMemsetAsync((void*)((int*)(ws + WS_FLAGS)), 0, 16 * sizeof(int), stream);
    const int nh2 = NPW + NCW;
    prep_weights<<<(nh2 + 255) / 256, 256, 0, stream>>>(w1, u1, w2, u2, ws);
    fused_lstm_kernel<<<2 * NG, 512, 0, stream>>>(
        s, conv_w, conv_b, b1, b2, dw, db, ws, (float*)d_out);
}

// Round 15
// 1844.565 us; speedup vs baseline: 2.0767x; 2.0767x over previous
//
#include <hip/hip_runtime.h>
#include <math.h>

// Conv1D(k=2,F=64,relu) -> LSTM1(H=100, relu cell, seq) -> LSTM2 (last) ->
// Dense(3) -> softmax.  B=128, T=2048, T'=2047.
//
// Round-20 = r17 (1857us best) with ONE change: per-step __syncthreads ->
// raw s_barrier with lgkmcnt(0)-only drain.
//  Rationale: __syncthreads emits s_waitcnt vmcnt(0) lgkmcnt(0) before
//  s_barrier (measured compiler behavior) -> the producer's per-step ring
//  stores to a remote XCD (~300-900cy) are drained EVERY step on the
//  critical path.  Raw barrier + lgkmcnt(0) keeps LDS exchange ordered
//  while ring stores stay in flight until the existing chunk-end
//  vmcnt(0) + release-flag (HK/AITER counted-vmcnt pattern, T4).
//  sched_barrier(0) fences guard against hoisting (rule #18).
//  Chunk-level barriers remain full __syncthreads.  r19 post-mortem: MFMA
//  batch-16 = 2.06x SLOWER (step latency is sync/transport-bound, not
//  instruction-bound) -> r17 structure confirmed; this targets its last
//  identified per-step latency component.

typedef _Float16 h2 __attribute__((ext_vector_type(2)));

#define TT 2048
#define TP 2047
#define HH 100
#define G4 400
#define FF 64
#define NB 128

#define X1R 176              // producer operand row halves (2x88)
#define CBQ 104              // consumer row halves (100 + pad4)
#define NPW (400 * 88)       // producer packed h2
#define NCW (400 * 100)      // consumer packed h2
#define CHK 64
#define NCHUNK 32
#define RINGC 4
#define CHUNK_DW (CHK * 50)  // 3200 dwords per ring slot

// ws layout in 4B units
#define WS_FLAGS (NPW + NCW)       // pflag[128], aflag[128]
#define WS_RING  (WS_FLAGS + 256)  // 128 * RINGC * CHUNK_DW dwords

#define FD2(w, xs, acc) acc = __builtin_amdgcn_fdot2(w, xs, acc, false)
#define B2(f) __builtin_bit_cast(h2, f)

// DPP quad_perm: 0xB1 = xor-1, 0x4E = xor-2 (proven r6-r17)
static __device__ __forceinline__ float psum2(float z) {
    int p = __builtin_amdgcn_update_dpp(0, __builtin_bit_cast(int, z),
                                        0xB1, 0xF, 0xF, true);
    return z + __builtin_bit_cast(float, p);
}
static __device__ __forceinline__ float xswap2(float z) {
    int p = __builtin_amdgcn_update_dpp(0, __builtin_bit_cast(int, z),
                                        0x4E, 0xF, 0xF, true);
    return __builtin_bit_cast(float, p);
}
static __device__ __forceinline__ float sig(float z) {
    return 1.0f / (1.0f + __expf(-z));
}
// per-step barrier: order LDS (lgkmcnt) but DO NOT drain vmcnt -- ring
// stores stay in flight across steps (drained once per chunk).
static __device__ __forceinline__ void step_barrier() {
    __builtin_amdgcn_sched_barrier(0);
    asm volatile("s_waitcnt lgkmcnt(0)" ::: "memory");
    __builtin_amdgcn_sched_barrier(0);
    __builtin_amdgcn_s_barrier();
    __builtin_amdgcn_sched_barrier(0);
}

// ---------------- prep kernel: pack weights f16 in per-thread order --------
// thread rt = (p<<2)|(g2<<1)|kh ; gates cL=(2*g2)*100+p, cH=cL+100.
// pack: float4 j = (a_{2j}, b_{2j}, a_{2j+1}, b_{2j+1})
__global__ void prep_weights(const float* __restrict__ w1, const float* __restrict__ u1,
                             const float* __restrict__ w2, const float* __restrict__ u2,
                             h2* __restrict__ ws)
{
    const int idx = blockIdx.x * 256 + threadIdx.x;
    if (idx >= NPW + NCW) return;
    float lo = 0.f, hi = 0.f;
    if (idx < NPW) {
        // producer: 88 h2/thread = 22 float4
        const int rt = idx / 88, r = idx % 88;
        const int qq = (r >> 2) * 2 + ((r & 3) >> 1);   // h2 pair index 0..43
        const int gs = r & 1;                           // 0 -> cL, 1 -> cH
        const int p = rt >> 2, g2 = (rt >> 1) & 1, kh = rt & 1;
        const int col = (2 * g2 + gs) * HH + p;
        const int E0 = 2 * qq;                          // in-half elem
#pragma unroll
        for (int e = 0; e < 2; ++e) {
            const int E = E0 + e;
            float v = 0.f;
            if (E < 82) {
                const int k = kh * 82 + E;              // orig combined-K index
                v = (k < FF) ? w1[k * G4 + col] : u1[(k - FF) * G4 + col];
            }
            if (e == 0) lo = v; else hi = v;
        }
    } else {
        // consumer: 100 h2/thread = 25 float4
        const int i2 = idx - NPW;
        const int rt = i2 / 100, r = i2 % 100;
        const int qq = (r >> 2) * 2 + ((r & 3) >> 1);   // 0..49
        const int gs = r & 1;
        const int p = rt >> 2, g2 = (rt >> 1) & 1, kh = rt & 1;
        const int col = (2 * g2 + gs) * HH + p;
        const int k0 = 2 * qq;
        const float* M = kh ? u2 : w2;
        lo = M[k0 * G4 + col];
        hi = M[(k0 + 1) * G4 + col];
    }
    ws[idx] = h2{(_Float16)lo, (_Float16)hi};
}

// ---------------- main kernel ----------------------------------------------
__global__ __launch_bounds__(512, 2)
void fused_lstm_kernel(const float* __restrict__ s,       // [B,T]
                       const float* __restrict__ conv_w,  // [2,1,F]
                       const float* __restrict__ conv_b,  // [F]
                       const float* __restrict__ b1,
                       const float* __restrict__ b2,
                       const float* __restrict__ dw, const float* __restrict__ db,
                       h2* __restrict__ wpk,              // weights + flags + ring
                       float* __restrict__ out)           // [B,3]
{
    const int tid  = threadIdx.x;
    const int bb   = blockIdx.x;
    const int b    = bb & (NB - 1);
    const bool prod = bb < NB;

    int* pflag = (int*)(wpk + WS_FLAGS) + b;
    int* aflag = (int*)(wpk + WS_FLAGS) + 128 + b;
    unsigned* ring = (unsigned*)(wpk + WS_RING) + (size_t)b * (RINGC * CHUNK_DW);

    __shared__ float s_buf[TT];                        // producer only
    __shared__ __align__(16) _Float16 X1[2 * X1R];     // producer operand ring
    __shared__ __align__(16) _Float16 CB[CHK * CBQ];   // consumer staged chunk
    __shared__ __align__(16) _Float16 HR[2 * CBQ];     // consumer h2 ring

    if (prod) {
        for (int i = tid; i < TT; i += 512) s_buf[i] = s[(size_t)b * TT + i];
        if (tid < X1R) ((unsigned*)X1)[tid] = 0u;      // both slots zero (pads stay 0)
    } else {
        if (tid < CBQ) ((unsigned*)HR)[tid] = 0u;      // 2*104 halves = 104 dwords
        if (tid < CHK * 2)                             // CB pad dwords [50,52)/row
            ((unsigned*)CB)[(tid >> 1) * 52 + 50 + (tid & 1)] = 0u;
    }
    __syncthreads();                                   // (A)

    if (prod) {
        // ================= PRODUCER block: conv + LSTM1 =================
        if (tid < 448) {
            const int rt = tid;
            const int active = rt < 400;
            const int lrt = active ? rt : 0;
            const int p  = lrt >> 2;
            const int g2 = (lrt >> 1) & 1;
            const int kh = lrt & 1;
            const int cL = (2 * g2) * HH + p;

            h2 wa[44], wb[44];
            {
                const float4* w4 = (const float4*)(wpk + (size_t)lrt * 88);
#pragma unroll
                for (int j = 0; j < 22; ++j) {
                    const float4 v = w4[j];
                    wa[2*j]   = B2(v.x); wb[2*j]   = B2(v.y);
                    wa[2*j+1] = B2(v.z); wb[2*j+1] = B2(v.w);
                }
            }
            const float bL = b1[cL], bH = b1[cL + HH];
            const int hoff = (p < 18) ? (64 + p) : (p + 70);  // h1[p] slot offset
            __syncthreads();                           // (B)

            float c = 0.0f;
            for (int t = 0; t < TP; ++t) {
                if ((t & 63) == 0) {                   // chunk start: ring credit
                    const int k = t >> 6;
                    if (tid == 0 && k >= RINGC) {
                        int g = 0;
                        while (__hip_atomic_load(aflag, __ATOMIC_ACQUIRE,
                                                 __HIP_MEMORY_SCOPE_AGENT) < k - (RINGC - 1)
                               && g < 50000000) { ++g; __builtin_amdgcn_s_sleep(8); }
                    }
                    __syncthreads();
                }
                if (active) {
                    _Float16* cur = X1 + (t & 1) * X1R;
                    _Float16* nx1 = X1 + ((t & 1) ^ 1) * X1R;
                    float za0 = 0.f, za1 = 0.f, zb0 = 0.f, zb1 = 0.f;
                    const float4* vb = (const float4*)(cur + kh * 88);
#pragma unroll
                    for (int r2 = 0; r2 < 11; ++r2) {
                        const float4 v = vb[r2];
                        FD2(wa[4*r2+0], B2(v.x), za0); FD2(wb[4*r2+0], B2(v.x), zb0);
                        FD2(wa[4*r2+1], B2(v.y), za1); FD2(wb[4*r2+1], B2(v.y), zb1);
                        FD2(wa[4*r2+2], B2(v.z), za0); FD2(wb[4*r2+2], B2(v.z), zb0);
                        FD2(wa[4*r2+3], B2(v.w), za1); FD2(wb[4*r2+3], B2(v.w), zb1);
                    }
                    const float zaS = psum2(za0 + za1) + bL;
                    const float zbS = psum2(zb0 + zb1) + bH;
                    const float oa = xswap2(zaS), ob = xswap2(zbS);
                    const float zi = g2 ? oa  : zaS;
                    const float zf = g2 ? ob  : zbS;
                    const float zg = g2 ? zaS : oa;
                    const float zo = g2 ? zbS : ob;
                    c = fmaf(sig(zf), c, sig(zi) * fmaxf(zg, 0.f));
                    const float h = sig(zo) * fmaxf(c, 0.f);
                    if ((rt & 3) == 0) {
                        const _Float16 hq = (_Float16)h;
                        nx1[hoff] = hq;                // h1 for LSTM1(t+1)
                        const unsigned hb = (unsigned)__builtin_bit_cast(unsigned short, hq);
                        const unsigned prt =
                            (unsigned)__builtin_amdgcn_ds_swizzle((int)hb, 0x101F) & 0xFFFFu;
                        if (!(p & 1))
                            __hip_atomic_store(ring + ((t >> 6) & 3) * CHUNK_DW
                                                    + (t & 63) * 50 + (p >> 1),
                                               hb | (prt << 16), __ATOMIC_RELAXED,
                                               __HIP_MEMORY_SCOPE_AGENT);
                    }
                    if (((t & 63) == 63) || (t == TP - 1))
                        asm volatile("s_waitcnt vmcnt(0)" ::: "memory");
                }
                step_barrier();                        // (C) one per step (no vm drain)
                if (tid == 0 && (((t & 63) == 63) || (t == TP - 1)))
                    __hip_atomic_fetch_add(pflag, 1, __ATOMIC_RELEASE,
                                           __HIP_MEMORY_SCOPE_AGENT);
            }
        } else {
            // conv wave: threads 448-511, one filter each
            const int f = tid - 448;
            const float cv0 = conv_w[f], cv1 = conv_w[FF + f], cb0 = conv_b[f];
            X1[f] = (_Float16)fmaxf(fmaf(s_buf[0], cv0, fmaf(s_buf[1], cv1, cb0)), 0.f);
            __syncthreads();                           // (B)
            for (int t = 0; t < TP; ++t) {
                if ((t & 63) == 0) __syncthreads();    // chunk-start companion
                if (t + 1 < TP) {
                    _Float16* nx1 = X1 + ((t & 1) ^ 1) * X1R;
                    nx1[f] = (_Float16)fmaxf(
                        fmaf(s_buf[t + 1], cv0, fmaf(s_buf[t + 2], cv1, cb0)), 0.f);
                }
                step_barrier();                        // (C)
            }
        }
    } else {
        // ================= CONSUMER block: LSTM2 + dense + softmax ==========
        if (tid < 448) {
            const int rt = tid;
            const int active = rt < 400;
            const int lrt = active ? rt : 0;
            const int p  = lrt >> 2;
            const int g2 = (lrt >> 1) & 1;
            const int kh = lrt & 1;
            const int cL = (2 * g2) * HH + p;

            h2 wa[50], wb[50];
            {
                const float4* w4 = (const float4*)(wpk + NPW + (size_t)lrt * 100);
#pragma unroll
                for (int j = 0; j < 25; ++j) {
                    const float4 v = w4[j];
                    wa[2*j]   = B2(v.x); wb[2*j]   = B2(v.y);
                    wa[2*j+1] = B2(v.z); wb[2*j+1] = B2(v.w);
                }
            }
            const float bL = b2[cL], bH = b2[cL + HH];
            __syncthreads();                           // (B)

            float c = 0.0f;
            for (int k = 0; k < NCHUNK; ++k) {
                if (tid == 0) {                        // wait for producer chunk k
                    int g = 0;
                    while (__hip_atomic_load(pflag, __ATOMIC_ACQUIRE,
                                             __HIP_MEMORY_SCOPE_AGENT) < k + 1
                           && g < 50000000) { ++g; __builtin_amdgcn_s_sleep(8); }
                }
                __syncthreads();                       // chunk ready
                const int csz = (TP - (k << 6) < CHK) ? (TP - (k << 6)) : CHK;
                unsigned* gsrc = ring + (k & 3) * CHUNK_DW;
                for (int d = tid; d < csz * 50; d += 448)
                    ((unsigned*)CB)[(d / 50) * 52 + (d % 50)] =
                        __hip_atomic_load(gsrc + d, __ATOMIC_RELAXED,
                                          __HIP_MEMORY_SCOPE_AGENT);
                __syncthreads();                       // staged
                if (tid == 0)
                    __hip_atomic_fetch_add(aflag, 1, __ATOMIC_RELAXED,
                                           __HIP_MEMORY_SCOPE_AGENT);
                for (int lt = 0; lt < csz; ++lt) {
                    const int t = (k << 6) + lt;
                    if (active) {
                        const _Float16* base = kh ? (HR + (t & 1) * CBQ)
                                                  : (CB + lt * CBQ);
                        float za0 = 0.f, za1 = 0.f, zb0 = 0.f, zb1 = 0.f;
                        const float4* vb = (const float4*)base;
#pragma unroll
                        for (int r2 = 0; r2 < 12; ++r2) {
                            const float4 v = vb[r2];
                            FD2(wa[4*r2+0], B2(v.x), za0); FD2(wb[4*r2+0], B2(v.x), zb0);
                            FD2(wa[4*r2+1], B2(v.y), za1); FD2(wb[4*r2+1], B2(v.y), zb1);
                            FD2(wa[4*r2+2], B2(v.z), za0); FD2(wb[4*r2+2], B2(v.z), zb0);
                            FD2(wa[4*r2+3], B2(v.w), za1); FD2(wb[4*r2+3], B2(v.w), zb1);
                        }
                        {                              // tail halves 96..99
                            const float2 tv = *(const float2*)(base + 96);
                            FD2(wa[48], B2(tv.x), za0); FD2(wb[48], B2(tv.x), zb0);
                            FD2(wa[49], B2(tv.y), za1); FD2(wb[49], B2(tv.y), zb1);
                        }
                        const float zaS = psum2(za0 + za1) + bL;
                        const float zbS = psum2(zb0 + zb1) + bH;
                        const float oa = xswap2(zaS), ob = xswap2(zbS);
                        const float zi = g2 ? oa  : zaS;
                        const float zf = g2 ? ob  : zbS;
                        const float zg = g2 ? zaS : oa;
                        const float zo = g2 ? zbS : ob;
                        c = fmaf(sig(zf), c, sig(zi) * fmaxf(zg, 0.f));
                        const float h = sig(zo) * fmaxf(c, 0.f);
                        if ((rt & 3) == 0)
                            HR[((t & 1) ^ 1) * CBQ + p] = (_Float16)h;
                    }
                    step_barrier();                    // (C)
                }
            }

            // final h2(t=2046) was written into slot ((2046&1)^1)=1
            if (rt == 0) {
                float l[3];
#pragma unroll
                for (int a = 0; a < 3; ++a) {
                    float acc = db[a];
                    for (int j = 0; j < HH; ++j)
                        acc = fmaf((float)HR[CBQ + j], dw[j * 3 + a], acc);
                    l[a] = acc;
                }
                const float m = fmaxf(l[0], fmaxf(l[1], l[2]));
                const float e0 = __expf(l[0] - m), e1 = __expf(l[1] - m), e2 = __expf(l[2] - m);
                const float inv = 1.0f / (e0 + e1 + e2);
                out[b * 3 + 0] = e0 * inv;
                out[b * 3 + 1] = e1 * inv;
                out[b * 3 + 2] = e2 * inv;
            }
        } else {
            // threads 448-511: barrier companions
            __syncthreads();                           // (B)
            for (int k = 0; k < NCHUNK; ++k) {
                __syncthreads();                       // chunk ready
                const int csz = (TP - (k << 6) < CHK) ? (TP - (k << 6)) : CHK;
                __syncthreads();                       // staged
                for (int lt = 0; lt < csz; ++lt)
                    step_barrier();                    // (C)
            }
        }
    }
}

// ---------------- launch ----------------------------------------------------
extern "C" void kernel_launch(void* const* d_in, const int* in_sizes, int n_in,
                              void* d_out, int out_size, void* d_ws, size_t ws_size,
                              hipStream_t stream) {
    const float* s      = (const float*)d_in[0];
    const float* conv_w = (const float*)d_in[1];
    const float* conv_b = (const float*)d_in[2];
    const float* w1     = (const float*)d_in[3];
    const float* u1     = (const float*)d_in[4];
    const float* b1     = (const float*)d_in[5];
    const float* w2     = (const float*)d_in[6];
    const float* u2     = (const float*)d_in[7];
    const float* b2     = (const float*)d_in[8];
    const float* dw     = (const float*)d_in[9];
    const float* db     = (const float*)d_in[10];

    h2* ws = (h2*)d_ws;
    hipMemsetAsync((void*)((int*)(ws + WS_FLAGS)), 0, 256 * sizeof(int), stream);
    const int nh2 = NPW + NCW;
    prep_weights<<<(nh2 + 255) / 256, 256, 0, stream>>>(w1, u1, w2, u2, ws);
    fused_lstm_kernel<<<256, 512, 0, stream>>>(
        s, conv_w, conv_b, b1, b2, dw, db, ws, (float*)d_out);
}